// Round 8
// baseline (424.928 us; speedup 1.0000x reference)
//
#include <hip/hip_runtime.h>
#include <hip/hip_bf16.h>

typedef __attribute__((ext_vector_type(4))) float  f32x4;
typedef __attribute__((ext_vector_type(8))) short  bf16x8;
typedef __attribute__((ext_vector_type(4))) unsigned u32x4;
typedef __attribute__((ext_vector_type(2))) unsigned u32x2;
typedef __attribute__((ext_vector_type(4))) int      i32x4;

#define NEG_SLOPE 0.01f
#define NBH 512   // histogram blocks appended to phase-1 grid

__device__ __forceinline__ unsigned short f2bf(float f) {
    unsigned u = __builtin_bit_cast(unsigned, f);
    return (unsigned short)((u + 0x7FFFu + ((u >> 16) & 1u)) >> 16);  // RNE
}
__device__ __forceinline__ unsigned pack2(float a, float b) {
    return (unsigned)f2bf(a) | ((unsigned)f2bf(b) << 16);
}

// ================= Phase 1 (fused): uv[node][256](bf16) GEMM + bucket histogram (LDS)
__global__ __launch_bounds__(256, 4)
void node_gemm_hist_kernel(const float* __restrict__ n_f,
                           const float* __restrict__ W_edge,      // [128][256]
                           unsigned short* __restrict__ uv,       // [n_nodes][256] bf16
                           int n_nodes,
                           const int* __restrict__ src_idx, int E,
                           int* __restrict__ hist, int nbuck, int shift,
                           int nb1)
{
    __shared__ short Ftile[64 * 128];   // 16 KB, swizzled

    const int tid = threadIdx.x;

    if ((int)blockIdx.x >= nb1) {       // ---- histogram blocks (LDS-aggregated)
        __shared__ int lh[1024];
        for (int i = tid; i < nbuck; i += 256) lh[i] = 0;
        __syncthreads();
        int b = blockIdx.x - nb1;
        for (int e = b * 256 + tid; e < E; e += NBH * 256)
            atomicAdd(&lh[src_idx[e] >> shift], 1);
        __syncthreads();
        for (int i = tid; i < nbuck; i += 256) {
            int c = lh[i];
            if (c) atomicAdd(&hist[i], c);
        }
        return;
    }

    const int lane = tid & 63;
    const int wave = tid >> 6;
    const int node_base = blockIdx.x * 64;

    #pragma unroll
    for (int it = 0; it < 4; ++it) {
        int r = it * 16 + (tid >> 4);
        int q = tid & 15;
        int gn = node_base + r;
        if (gn >= n_nodes) gn = n_nodes - 1;
        const float* p = n_f + (size_t)gn * 128 + q * 8;
        f32x4 v0 = *(const f32x4*)p;
        f32x4 v1 = *(const f32x4*)(p + 4);
        u32x4 u;
        u.x = pack2(v0.x, v0.y);
        u.y = pack2(v0.z, v0.w);
        u.z = pack2(v1.x, v1.y);
        u.w = pack2(v1.z, v1.w);
        int byteoff = (r * 256 + q * 16) ^ ((r & 7) << 4);
        *(u32x4*)((char*)Ftile + byteoff) = u;
    }

    const int an    = lane & 15;
    const int ak    = (lane >> 4) * 8;
    const int kofs  = (wave >= 2) ? 128 : 0;
    const int obase = (wave & 1) * 64;
    bf16x8 wfrag[4][4];
    #pragma unroll
    for (int nt = 0; nt < 4; ++nt) {
        #pragma unroll
        for (int kt = 0; kt < 4; ++kt) {
            const float* wp = W_edge + (size_t)(obase + nt * 16 + an) * 256 + kofs + kt * 32 + ak;
            f32x4 w0 = *(const f32x4*)wp;
            f32x4 w1 = *(const f32x4*)(wp + 4);
            bf16x8 f;
            f[0] = (short)f2bf(w0.x); f[1] = (short)f2bf(w0.y);
            f[2] = (short)f2bf(w0.z); f[3] = (short)f2bf(w0.w);
            f[4] = (short)f2bf(w1.x); f[5] = (short)f2bf(w1.y);
            f[6] = (short)f2bf(w1.z); f[7] = (short)f2bf(w1.w);
            wfrag[nt][kt] = f;
        }
    }

    __syncthreads();

    const int fe    = lane & 15;
    const int fkoff = (lane >> 4) * 16;
    #pragma unroll
    for (int mt = 0; mt < 4; ++mt) {
        f32x4 acc[4];
        #pragma unroll
        for (int nt = 0; nt < 4; ++nt) acc[nt] = (f32x4){0.f, 0.f, 0.f, 0.f};
        const int row = mt * 16 + fe;
        #pragma unroll
        for (int kt = 0; kt < 4; ++kt) {
            int byteoff = (row * 256 + kt * 64 + fkoff) ^ ((row & 7) << 4);
            bf16x8 ffrag = *(const bf16x8*)((const char*)Ftile + byteoff);
            #pragma unroll
            for (int nt = 0; nt < 4; ++nt)
                acc[nt] = __builtin_amdgcn_mfma_f32_16x16x32_bf16(wfrag[nt][kt], ffrag, acc[nt], 0, 0, 0);
        }
        int gn = node_base + mt * 16 + fe;
        if (gn < n_nodes) {
            unsigned short* op = uv + (size_t)gn * 256 + wave * 64 + (lane >> 4) * 4;
            #pragma unroll
            for (int nt = 0; nt < 4; ++nt) {
                u32x2 pk;
                pk.x = pack2(acc[nt][0], acc[nt][1]);
                pk.y = pack2(acc[nt][2], acc[nt][3]);
                *(u32x2*)(op + nt * 16) = pk;
            }
        }
    }
}

// ================= single-pass exclusive scan (n <= 1024)
__global__ __launch_bounds__(1024, 1)
void scan_small_kernel(const int* __restrict__ hist, int* __restrict__ offs, int n)
{
    __shared__ int wtot[16];
    const int tid  = threadIdx.x;
    const int lane = tid & 63;
    const int wid  = tid >> 6;

    int x = (tid < n) ? hist[tid] : 0;
    int v = x;
    #pragma unroll
    for (int d = 1; d < 64; d <<= 1) {
        int t = __shfl_up(v, d);
        if (lane >= d) v += t;
    }
    if (lane == 63) wtot[wid] = v;
    __syncthreads();
    if (wid == 0) {
        int wv = (lane < 16) ? wtot[lane] : 0;
        #pragma unroll
        for (int d = 1; d < 16; d <<= 1) {
            int t = __shfl_up(wv, d);
            if (lane >= d) wv += t;
        }
        if (lane < 16) wtot[lane] = wv;
    }
    __syncthreads();
    int wbase = (wid == 0) ? 0 : wtot[wid - 1];
    if (tid < n) offs[tid] = wbase + v - x;
}

// ================= scatter: bucket edges by src>>shift, pack (src,dst,e) int4
__global__ __launch_bounds__(256, 8)
void scatter_bucket_kernel(const int* __restrict__ src_idx,
                           const int* __restrict__ dst_idx,
                           int* __restrict__ offs, int shift,
                           i32x4* __restrict__ sorted, int E)
{
    for (int e = blockIdx.x * 256 + threadIdx.x; e < E; e += gridDim.x * 256) {
        int s = src_idx[e];
        int b = s >> shift;
        int pos = atomicAdd(&offs[b], 1);
        i32x4 rec;
        rec.x = s; rec.y = dst_idx[e]; rec.z = e; rec.w = 0;
        sorted[pos] = rec;
    }
}

// ================= Phase 2 compute helper (dense NT e_out, cached a_out)
__device__ __forceinline__ void edge_compute_store(u32x2 du0, u32x2 du1,
                                                   u32x2 dv0, u32x2 dv1,
                                                   const f32x4& wa_lo, const f32x4& wa_hi,
                                                   float* __restrict__ e_out,
                                                   float* __restrict__ a_out,
                                                   int e, bool valid, int q)
{
    f32x4 r0, r1;
    #pragma unroll
    for (int j = 0; j < 2; ++j) {
        float ulo = __builtin_bit_cast(float, du0[j] << 16);
        float uhi = __builtin_bit_cast(float, du0[j] & 0xFFFF0000u);
        float vlo = __builtin_bit_cast(float, dv0[j] << 16);
        float vhi = __builtin_bit_cast(float, dv0[j] & 0xFFFF0000u);
        r0[2*j]   = fmaxf(ulo + vlo, 0.f);
        r0[2*j+1] = fmaxf(uhi + vhi, 0.f);

        float ulo1 = __builtin_bit_cast(float, du1[j] << 16);
        float uhi1 = __builtin_bit_cast(float, du1[j] & 0xFFFF0000u);
        float vlo1 = __builtin_bit_cast(float, dv1[j] << 16);
        float vhi1 = __builtin_bit_cast(float, dv1[j] & 0xFFFF0000u);
        r1[2*j]   = fmaxf(ulo1 + vlo1, 0.f);
        r1[2*j+1] = fmaxf(uhi1 + vhi1, 0.f);
    }

    if (valid) {
        float* ep = e_out + (size_t)e * 128;
        __builtin_nontemporal_store(r0, (f32x4*)(ep + q * 4));
        __builtin_nontemporal_store(r1, (f32x4*)(ep + 64 + q * 4));
    }

    float pd = r0[0]*wa_lo[0] + r0[1]*wa_lo[1] + r0[2]*wa_lo[2] + r0[3]*wa_lo[3]
             + r1[0]*wa_hi[0] + r1[1]*wa_hi[1] + r1[2]*wa_hi[2] + r1[3]*wa_hi[3];
    pd += __shfl_xor(pd, 1);
    pd += __shfl_xor(pd, 2);
    pd += __shfl_xor(pd, 4);
    pd += __shfl_xor(pd, 8);
    if (valid && q == 0) {
        float a = (pd > 0.f) ? pd : NEG_SLOPE * pd;
        a_out[e] = a;   // cached store: random addr, let L2 merge lines
    }
}

// ================= Phase 2 (bucket-sorted edge stream)
__global__ __launch_bounds__(256, 8)
void edge_apply_sorted_kernel(const i32x4* __restrict__ sorted,
                              const unsigned short* __restrict__ uv,
                              const float* __restrict__ W_attn,
                              float* __restrict__ e_out,
                              float* __restrict__ a_out,
                              int E)
{
    const int tid  = threadIdx.x;
    const int lane = tid & 63;
    const int wave = tid >> 6;
    const int q    = lane & 15;
    const int sub  = lane >> 4;

    const f32x4 wa_lo = *(const f32x4*)&W_attn[q * 4];
    const f32x4 wa_hi = *(const f32x4*)&W_attn[64 + q * 4];

    const int gw     = blockIdx.x * 4 + wave;
    const int stride = gridDim.x * 4 * 8;

    for (int e0 = gw * 8; e0 < E; e0 += stride) {
        int  iA = e0 + sub;
        int  iB = e0 + 4 + sub;
        bool vA = (iA < E);
        bool vB = (iB < E);
        i32x4 rA = sorted[vA ? iA : 0];
        i32x4 rB = sorted[vB ? iB : 0];

        const unsigned short* upA = uv + (size_t)rA.x * 256;
        const unsigned short* vpA = uv + (size_t)rA.y * 256 + 128;
        const unsigned short* upB = uv + (size_t)rB.x * 256;
        const unsigned short* vpB = uv + (size_t)rB.y * 256 + 128;
        u32x2 du0A = *(const u32x2*)(upA + q * 4);
        u32x2 du1A = *(const u32x2*)(upA + 64 + q * 4);
        u32x2 dv0A = *(const u32x2*)(vpA + q * 4);
        u32x2 dv1A = *(const u32x2*)(vpA + 64 + q * 4);
        u32x2 du0B = *(const u32x2*)(upB + q * 4);
        u32x2 du1B = *(const u32x2*)(upB + 64 + q * 4);
        u32x2 dv0B = *(const u32x2*)(vpB + q * 4);
        u32x2 dv1B = *(const u32x2*)(vpB + 64 + q * 4);

        edge_compute_store(du0A, du1A, dv0A, dv1A, wa_lo, wa_hi, e_out, a_out, rA.z, vA, q);
        edge_compute_store(du0B, du1B, dv0B, dv1B, wa_lo, wa_hi, e_out, a_out, rB.z, vB, q);
    }
}

// ================= Phase 2 (unsorted fallback, R6)
__global__ __launch_bounds__(256, 8)
void edge_apply_kernel(const int*   __restrict__ src_idx,
                       const int*   __restrict__ dst_idx,
                       const unsigned short* __restrict__ uv,
                       const float* __restrict__ W_attn,
                       float* __restrict__ e_out,
                       float* __restrict__ a_out,
                       int E)
{
    const int tid  = threadIdx.x;
    const int lane = tid & 63;
    const int wave = tid >> 6;
    const int q    = lane & 15;
    const int sub  = lane >> 4;

    const f32x4 wa_lo = *(const f32x4*)&W_attn[q * 4];
    const f32x4 wa_hi = *(const f32x4*)&W_attn[64 + q * 4];

    const int gw     = blockIdx.x * 4 + wave;
    const int stride = gridDim.x * 4 * 8;

    for (int e0 = gw * 8; e0 < E; e0 += stride) {
        int  eA = e0 + sub;
        int  eB = e0 + 4 + sub;
        bool vA = (eA < E);
        bool vB = (eB < E);
        int  esA = vA ? src_idx[eA] : 0;
        int  edA = vA ? dst_idx[eA] : 0;
        int  esB = vB ? src_idx[eB] : 0;
        int  edB = vB ? dst_idx[eB] : 0;

        const unsigned short* upA = uv + (size_t)esA * 256;
        const unsigned short* vpA = uv + (size_t)edA * 256 + 128;
        const unsigned short* upB = uv + (size_t)esB * 256;
        const unsigned short* vpB = uv + (size_t)edB * 256 + 128;
        u32x2 du0A = *(const u32x2*)(upA + q * 4);
        u32x2 du1A = *(const u32x2*)(upA + 64 + q * 4);
        u32x2 dv0A = *(const u32x2*)(vpA + q * 4);
        u32x2 dv1A = *(const u32x2*)(vpA + 64 + q * 4);
        u32x2 du0B = *(const u32x2*)(upB + q * 4);
        u32x2 du1B = *(const u32x2*)(upB + 64 + q * 4);
        u32x2 dv0B = *(const u32x2*)(vpB + q * 4);
        u32x2 dv1B = *(const u32x2*)(vpB + 64 + q * 4);

        edge_compute_store(du0A, du1A, dv0A, dv1A, wa_lo, wa_hi, e_out, a_out, eA, vA, q);
        edge_compute_store(du0B, du1B, dv0B, dv1B, wa_lo, wa_hi, e_out, a_out, eB, vB, q);
    }
}

// ================= Final fallback (tiny ws): fused kernel from R2
#define ME 64
__global__ __launch_bounds__(256, 4)
void gat_edge_fused_kernel(const float* __restrict__ n_f,
                           const int*   __restrict__ src_idx,
                           const int*   __restrict__ dst_idx,
                           const float* __restrict__ W_edge,
                           const float* __restrict__ W_attn,
                           float* __restrict__ e_out,
                           float* __restrict__ a_out,
                           int E)
{
    __shared__ short Atile[ME * 256];
    __shared__ float a_acc[ME];

    const int tid  = threadIdx.x;
    const int lane = tid & 63;
    const int wave = tid >> 6;
    const int edge_base = blockIdx.x * ME;

    if (tid < ME) a_acc[tid] = 0.0f;

    #pragma unroll
    for (int it = 0; it < 8; ++it) {
        int pair = it * 16 + (tid >> 4);
        int e  = pair >> 1;
        int hf = pair & 1;
        int q  = tid & 15;
        int ge = edge_base + e;
        int idx = (ge < E) ? (hf ? dst_idx[ge] : src_idx[ge]) : 0;
        const float* p = n_f + (size_t)idx * 128 + q * 8;
        f32x4 v0 = *(const f32x4*)p;
        f32x4 v1 = *(const f32x4*)(p + 4);
        u32x4 u;
        u.x = pack2(v0.x, v0.y);
        u.y = pack2(v0.z, v0.w);
        u.z = pack2(v1.x, v1.y);
        u.w = pack2(v1.z, v1.w);
        int byteoff = (e * 512 + hf * 256 + q * 16) ^ ((e & 7) << 4);
        *(u32x4*)((char*)Atile + byteoff) = u;
    }

    const int an = lane & 15;
    const int ak = (lane >> 4) * 8;
    const int n0 = wave * 32;
    bf16x8 wfrag[2][8];
    #pragma unroll
    for (int nt = 0; nt < 2; ++nt) {
        #pragma unroll
        for (int kt = 0; kt < 8; ++kt) {
            const float* wp = W_edge + (size_t)(n0 + nt * 16 + an) * 256 + kt * 32 + ak;
            f32x4 w0 = *(const f32x4*)wp;
            f32x4 w1 = *(const f32x4*)(wp + 4);
            bf16x8 f;
            f[0] = (short)f2bf(w0.x); f[1] = (short)f2bf(w0.y);
            f[2] = (short)f2bf(w0.z); f[3] = (short)f2bf(w0.w);
            f[4] = (short)f2bf(w1.x); f[5] = (short)f2bf(w1.y);
            f[6] = (short)f2bf(w1.z); f[7] = (short)f2bf(w1.w);
            wfrag[nt][kt] = f;
        }
    }
    f32x4 wa[2];
    wa[0] = *(const f32x4*)&W_attn[n0 + (lane >> 4) * 4];
    wa[1] = *(const f32x4*)&W_attn[n0 + 16 + (lane >> 4) * 4];

    __syncthreads();

    const int fe    = lane & 15;
    const int fkoff = (lane >> 4) * 16;
    #pragma unroll
    for (int et = 0; et < 4; ++et) {
        const int erow = et * 16 + fe;
        f32x4 acc0 = {0.f, 0.f, 0.f, 0.f};
        f32x4 acc1 = {0.f, 0.f, 0.f, 0.f};
        #pragma unroll
        for (int kt = 0; kt < 8; ++kt) {
            int byteoff = (erow * 512 + kt * 64 + fkoff) ^ ((erow & 7) << 4);
            bf16x8 ffrag = *(const bf16x8*)((const char*)Atile + byteoff);
            acc0 = __builtin_amdgcn_mfma_f32_16x16x32_bf16(wfrag[0][kt], ffrag, acc0, 0, 0, 0);
            acc1 = __builtin_amdgcn_mfma_f32_16x16x32_bf16(wfrag[1][kt], ffrag, acc1, 0, 0, 0);
        }
        const int ge = edge_base + et * 16 + fe;
        f32x4 c0, c1;
        #pragma unroll
        for (int j = 0; j < 4; ++j) {
            c0[j] = fmaxf(acc0[j], 0.f);
            c1[j] = fmaxf(acc1[j], 0.f);
        }
        if (ge < E) {
            float* ep = e_out + (size_t)ge * 128 + n0 + (lane >> 4) * 4;
            *(f32x4*)ep        = c0;
            *(f32x4*)(ep + 16) = c1;
        }
        float pdot = c0[0]*wa[0][0] + c0[1]*wa[0][1] + c0[2]*wa[0][2] + c0[3]*wa[0][3]
                   + c1[0]*wa[1][0] + c1[1]*wa[1][1] + c1[2]*wa[1][2] + c1[3]*wa[1][3];
        pdot += __shfl_xor(pdot, 16);
        pdot += __shfl_xor(pdot, 32);
        if (lane < 16) atomicAdd(&a_acc[et * 16 + lane], pdot);
    }

    __syncthreads();
    if (tid < ME) {
        int ge = edge_base + tid;
        if (ge < E) {
            float a = a_acc[tid];
            a_out[ge] = (a > 0.f) ? a : NEG_SLOPE * a;
        }
    }
}

extern "C" void kernel_launch(void* const* d_in, const int* in_sizes, int n_in,
                              void* d_out, int out_size, void* d_ws, size_t ws_size,
                              hipStream_t stream) {
    const float* n_f     = (const float*)d_in[0];
    const int*   src_idx = (const int*)d_in[1];
    const int*   dst_idx = (const int*)d_in[2];
    const float* W_edge  = (const float*)d_in[3];
    const float* W_attn  = (const float*)d_in[4];
    const int E       = in_sizes[1];
    const int n_nodes = in_sizes[0] / 128;

    float* e_out = (float*)d_out;
    float* a_out = e_out + (size_t)E * 128;

    // bucket shift: buckets of 64 src nodes, capped at 1024 buckets
    int shift = 6;
    while (((n_nodes + (1 << shift) - 1) >> shift) > 1024) ++shift;
    const int nbuck = (n_nodes + (1 << shift) - 1) >> shift;

    // ws layout (16B-aligned slices)
    const size_t uv_b    = (size_t)n_nodes * 256 * sizeof(unsigned short);
    const size_t off_uv  = 0;
    const size_t off_srt = (off_uv + uv_b + 15) & ~(size_t)15;
    const size_t off_hi  = (off_srt + (size_t)E * 16 + 15) & ~(size_t)15;
    const size_t off_of  = (off_hi + (size_t)nbuck * 4 + 15) & ~(size_t)15;
    const size_t total   = off_of + (size_t)nbuck * 4;

    char* ws = (char*)d_ws;
    if (ws_size >= total) {
        unsigned short* uv = (unsigned short*)(ws + off_uv);
        i32x4* sorted = (i32x4*)(ws + off_srt);
        int* hist = (int*)(ws + off_hi);
        int* offs = (int*)(ws + off_of);

        int nb1 = (n_nodes + 63) / 64;
        hipMemsetAsync(hist, 0, (size_t)nbuck * 4, stream);
        node_gemm_hist_kernel<<<nb1 + NBH, 256, 0, stream>>>(n_f, W_edge, uv, n_nodes,
                                                             src_idx, E, hist, nbuck, shift, nb1);
        scan_small_kernel<<<1, 1024, 0, stream>>>(hist, offs, nbuck);
        scatter_bucket_kernel<<<1024, 256, 0, stream>>>(src_idx, dst_idx, offs, shift,
                                                        sorted, E);
        edge_apply_sorted_kernel<<<2048, 256, 0, stream>>>(sorted, uv, W_attn,
                                                           e_out, a_out, E);
    } else if (ws_size >= uv_b) {
        unsigned short* uv = (unsigned short*)ws;
        int nb1 = (n_nodes + 63) / 64;
        node_gemm_hist_kernel<<<nb1, 256, 0, stream>>>(n_f, W_edge, uv, n_nodes,
                                                       src_idx, E, (int*)nullptr, nbuck, shift, nb1);
        edge_apply_kernel<<<2048, 256, 0, stream>>>(src_idx, dst_idx, uv, W_attn,
                                                    e_out, a_out, E);
    } else {
        int nblocks = (E + ME - 1) / ME;
        gat_edge_fused_kernel<<<nblocks, 256, 0, stream>>>(n_f, src_idx, dst_idx,
                                                           W_edge, W_attn, e_out, a_out, E);
    }
}

// Round 9
// 185.063 us; speedup vs baseline: 2.2961x; 2.2961x over previous
//
#include <hip/hip_runtime.h>
#include <hip/hip_bf16.h>

typedef __attribute__((ext_vector_type(4))) float  f32x4;
typedef __attribute__((ext_vector_type(8))) short  bf16x8;
typedef __attribute__((ext_vector_type(4))) unsigned u32x4;
typedef __attribute__((ext_vector_type(2))) unsigned u32x2;

#define NEG_SLOPE 0.01f

__device__ __forceinline__ unsigned short f2bf(float f) {
    unsigned u = __builtin_bit_cast(unsigned, f);
    return (unsigned short)((u + 0x7FFFu + ((u >> 16) & 1u)) >> 16);  // RNE
}
__device__ __forceinline__ unsigned pack2(float a, float b) {
    return (unsigned)f2bf(a) | ((unsigned)f2bf(b) << 16);
}

// ================= Phase 1: uv[node][256] (bf16) = [ n_f @ W_src^T | n_f @ W_dst^T ]
__global__ __launch_bounds__(256, 4)
void node_gemm_kernel(const float* __restrict__ n_f,
                      const float* __restrict__ W_edge,        // [128][256]
                      unsigned short* __restrict__ uv,         // [n_nodes][256] bf16
                      int n_nodes)
{
    __shared__ short Ftile[64 * 128];   // 16 KB, swizzled

    const int tid  = threadIdx.x;
    const int lane = tid & 63;
    const int wave = tid >> 6;
    const int node_base = blockIdx.x * 64;

    #pragma unroll
    for (int it = 0; it < 4; ++it) {
        int r = it * 16 + (tid >> 4);
        int q = tid & 15;
        int gn = node_base + r;
        if (gn >= n_nodes) gn = n_nodes - 1;
        const float* p = n_f + (size_t)gn * 128 + q * 8;
        f32x4 v0 = *(const f32x4*)p;
        f32x4 v1 = *(const f32x4*)(p + 4);
        u32x4 u;
        u.x = pack2(v0.x, v0.y);
        u.y = pack2(v0.z, v0.w);
        u.z = pack2(v1.x, v1.y);
        u.w = pack2(v1.z, v1.w);
        int byteoff = (r * 256 + q * 16) ^ ((r & 7) << 4);
        *(u32x4*)((char*)Ftile + byteoff) = u;
    }

    const int an    = lane & 15;
    const int ak    = (lane >> 4) * 8;
    const int kofs  = (wave >= 2) ? 128 : 0;
    const int obase = (wave & 1) * 64;
    bf16x8 wfrag[4][4];
    #pragma unroll
    for (int nt = 0; nt < 4; ++nt) {
        #pragma unroll
        for (int kt = 0; kt < 4; ++kt) {
            const float* wp = W_edge + (size_t)(obase + nt * 16 + an) * 256 + kofs + kt * 32 + ak;
            f32x4 w0 = *(const f32x4*)wp;
            f32x4 w1 = *(const f32x4*)(wp + 4);
            bf16x8 f;
            f[0] = (short)f2bf(w0.x); f[1] = (short)f2bf(w0.y);
            f[2] = (short)f2bf(w0.z); f[3] = (short)f2bf(w0.w);
            f[4] = (short)f2bf(w1.x); f[5] = (short)f2bf(w1.y);
            f[6] = (short)f2bf(w1.z); f[7] = (short)f2bf(w1.w);
            wfrag[nt][kt] = f;
        }
    }

    __syncthreads();

    const int fe    = lane & 15;
    const int fkoff = (lane >> 4) * 16;
    #pragma unroll
    for (int mt = 0; mt < 4; ++mt) {
        f32x4 acc[4];
        #pragma unroll
        for (int nt = 0; nt < 4; ++nt) acc[nt] = (f32x4){0.f, 0.f, 0.f, 0.f};
        const int row = mt * 16 + fe;
        #pragma unroll
        for (int kt = 0; kt < 4; ++kt) {
            int byteoff = (row * 256 + kt * 64 + fkoff) ^ ((row & 7) << 4);
            bf16x8 ffrag = *(const bf16x8*)((const char*)Ftile + byteoff);
            #pragma unroll
            for (int nt = 0; nt < 4; ++nt)
                acc[nt] = __builtin_amdgcn_mfma_f32_16x16x32_bf16(wfrag[nt][kt], ffrag, acc[nt], 0, 0, 0);
        }
        int gn = node_base + mt * 16 + fe;
        if (gn < n_nodes) {
            unsigned short* op = uv + (size_t)gn * 256 + wave * 64 + (lane >> 4) * 4;
            #pragma unroll
            for (int nt = 0; nt < 4; ++nt) {
                u32x2 pk;
                pk.x = pack2(acc[nt][0], acc[nt][1]);
                pk.y = pack2(acc[nt][2], acc[nt][3]);
                *(u32x2*)(op + nt * 16) = pk;
            }
        }
    }
}

// ================= Phase 2: per-edge streaming (bf16 uv, dense NT stores)
// lane q owns cols [4q,4q+4) and [64+4q,64+4q+4) -> every 16B store inst is
// CONTIGUOUS across the 16-lane group (256 B dense spans, full 64B lines).
__device__ __forceinline__ void edge_compute_store(u32x2 du0, u32x2 du1,
                                                   u32x2 dv0, u32x2 dv1,
                                                   const f32x4& wa_lo, const f32x4& wa_hi,
                                                   float* __restrict__ e_out,
                                                   float* __restrict__ a_out,
                                                   int e, bool valid, int q)
{
    f32x4 r0, r1;
    #pragma unroll
    for (int j = 0; j < 2; ++j) {
        float ulo = __builtin_bit_cast(float, du0[j] << 16);
        float uhi = __builtin_bit_cast(float, du0[j] & 0xFFFF0000u);
        float vlo = __builtin_bit_cast(float, dv0[j] << 16);
        float vhi = __builtin_bit_cast(float, dv0[j] & 0xFFFF0000u);
        r0[2*j]   = fmaxf(ulo + vlo, 0.f);
        r0[2*j+1] = fmaxf(uhi + vhi, 0.f);

        float ulo1 = __builtin_bit_cast(float, du1[j] << 16);
        float uhi1 = __builtin_bit_cast(float, du1[j] & 0xFFFF0000u);
        float vlo1 = __builtin_bit_cast(float, dv1[j] << 16);
        float vhi1 = __builtin_bit_cast(float, dv1[j] & 0xFFFF0000u);
        r1[2*j]   = fmaxf(ulo1 + vlo1, 0.f);
        r1[2*j+1] = fmaxf(uhi1 + vhi1, 0.f);
    }

    if (valid) {
        float* ep = e_out + (size_t)e * 128;
        __builtin_nontemporal_store(r0, (f32x4*)(ep + q * 4));
        __builtin_nontemporal_store(r1, (f32x4*)(ep + 64 + q * 4));
    }

    float pd = r0[0]*wa_lo[0] + r0[1]*wa_lo[1] + r0[2]*wa_lo[2] + r0[3]*wa_lo[3]
             + r1[0]*wa_hi[0] + r1[1]*wa_hi[1] + r1[2]*wa_hi[2] + r1[3]*wa_hi[3];
    pd += __shfl_xor(pd, 1);
    pd += __shfl_xor(pd, 2);
    pd += __shfl_xor(pd, 4);
    pd += __shfl_xor(pd, 8);
    if (valid && q == 0) {
        float a = (pd > 0.f) ? pd : NEG_SLOPE * pd;
        __builtin_nontemporal_store(a, a_out + e);
    }
}

__global__ __launch_bounds__(256, 8)
void edge_apply_kernel(const int*   __restrict__ src_idx,
                       const int*   __restrict__ dst_idx,
                       const unsigned short* __restrict__ uv,  // [n_nodes][256] bf16
                       const float* __restrict__ W_attn,       // [128]
                       float* __restrict__ e_out,              // [E][128]
                       float* __restrict__ a_out,              // [E]
                       int E)
{
    const int tid  = threadIdx.x;
    const int lane = tid & 63;
    const int wave = tid >> 6;
    const int q    = lane & 15;   // 4-elem chunk owner within each half-row
    const int sub  = lane >> 4;   // edge within group of 4

    const f32x4 wa_lo = *(const f32x4*)&W_attn[q * 4];
    const f32x4 wa_hi = *(const f32x4*)&W_attn[64 + q * 4];

    const int gw     = blockIdx.x * 4 + wave;
    const int stride = gridDim.x * 4 * 8;   // 8 edges per wave per iter

    for (int e0 = gw * 8; e0 < E; e0 += stride) {
        int  eA = e0 + sub;
        int  eB = e0 + 4 + sub;
        bool vA = (eA < E);
        bool vB = (eB < E);
        int  esA = vA ? src_idx[eA] : 0;
        int  edA = vA ? dst_idx[eA] : 0;
        int  esB = vB ? src_idx[eB] : 0;
        int  edB = vB ? dst_idx[eB] : 0;

        // issue all 8 gathers before any compute (MLP)
        const unsigned short* upA = uv + (size_t)esA * 256;
        const unsigned short* vpA = uv + (size_t)edA * 256 + 128;
        const unsigned short* upB = uv + (size_t)esB * 256;
        const unsigned short* vpB = uv + (size_t)edB * 256 + 128;
        u32x2 du0A = *(const u32x2*)(upA + q * 4);
        u32x2 du1A = *(const u32x2*)(upA + 64 + q * 4);
        u32x2 dv0A = *(const u32x2*)(vpA + q * 4);
        u32x2 dv1A = *(const u32x2*)(vpA + 64 + q * 4);
        u32x2 du0B = *(const u32x2*)(upB + q * 4);
        u32x2 du1B = *(const u32x2*)(upB + 64 + q * 4);
        u32x2 dv0B = *(const u32x2*)(vpB + q * 4);
        u32x2 dv1B = *(const u32x2*)(vpB + 64 + q * 4);

        edge_compute_store(du0A, du1A, dv0A, dv1A, wa_lo, wa_hi, e_out, a_out, eA, vA, q);
        edge_compute_store(du0B, du1B, dv0B, dv1B, wa_lo, wa_hi, e_out, a_out, eB, vB, q);
    }
}

// ================= Fallback (ws too small): fused kernel from R2 =================
#define ME 64
__global__ __launch_bounds__(256, 4)
void gat_edge_fused_kernel(const float* __restrict__ n_f,
                           const int*   __restrict__ src_idx,
                           const int*   __restrict__ dst_idx,
                           const float* __restrict__ W_edge,
                           const float* __restrict__ W_attn,
                           float* __restrict__ e_out,
                           float* __restrict__ a_out,
                           int E)
{
    __shared__ short Atile[ME * 256];
    __shared__ float a_acc[ME];

    const int tid  = threadIdx.x;
    const int lane = tid & 63;
    const int wave = tid >> 6;
    const int edge_base = blockIdx.x * ME;

    if (tid < ME) a_acc[tid] = 0.0f;

    #pragma unroll
    for (int it = 0; it < 8; ++it) {
        int pair = it * 16 + (tid >> 4);
        int e  = pair >> 1;
        int hf = pair & 1;
        int q  = tid & 15;
        int ge = edge_base + e;
        int idx = (ge < E) ? (hf ? dst_idx[ge] : src_idx[ge]) : 0;
        const float* p = n_f + (size_t)idx * 128 + q * 8;
        f32x4 v0 = *(const f32x4*)p;
        f32x4 v1 = *(const f32x4*)(p + 4);
        u32x4 u;
        u.x = pack2(v0.x, v0.y);
        u.y = pack2(v0.z, v0.w);
        u.z = pack2(v1.x, v1.y);
        u.w = pack2(v1.z, v1.w);
        int byteoff = (e * 512 + hf * 256 + q * 16) ^ ((e & 7) << 4);
        *(u32x4*)((char*)Atile + byteoff) = u;
    }

    const int an = lane & 15;
    const int ak = (lane >> 4) * 8;
    const int n0 = wave * 32;
    bf16x8 wfrag[2][8];
    #pragma unroll
    for (int nt = 0; nt < 2; ++nt) {
        #pragma unroll
        for (int kt = 0; kt < 8; ++kt) {
            const float* wp = W_edge + (size_t)(n0 + nt * 16 + an) * 256 + kt * 32 + ak;
            f32x4 w0 = *(const f32x4*)wp;
            f32x4 w1 = *(const f32x4*)(wp + 4);
            bf16x8 f;
            f[0] = (short)f2bf(w0.x); f[1] = (short)f2bf(w0.y);
            f[2] = (short)f2bf(w0.z); f[3] = (short)f2bf(w0.w);
            f[4] = (short)f2bf(w1.x); f[5] = (short)f2bf(w1.y);
            f[6] = (short)f2bf(w1.z); f[7] = (short)f2bf(w1.w);
            wfrag[nt][kt] = f;
        }
    }
    f32x4 wa[2];
    wa[0] = *(const f32x4*)&W_attn[n0 + (lane >> 4) * 4];
    wa[1] = *(const f32x4*)&W_attn[n0 + 16 + (lane >> 4) * 4];

    __syncthreads();

    const int fe    = lane & 15;
    const int fkoff = (lane >> 4) * 16;
    #pragma unroll
    for (int et = 0; et < 4; ++et) {
        const int erow = et * 16 + fe;
        f32x4 acc0 = {0.f, 0.f, 0.f, 0.f};
        f32x4 acc1 = {0.f, 0.f, 0.f, 0.f};
        #pragma unroll
        for (int kt = 0; kt < 8; ++kt) {
            int byteoff = (erow * 512 + kt * 64 + fkoff) ^ ((erow & 7) << 4);
            bf16x8 ffrag = *(const bf16x8*)((const char*)Atile + byteoff);
            acc0 = __builtin_amdgcn_mfma_f32_16x16x32_bf16(wfrag[0][kt], ffrag, acc0, 0, 0, 0);
            acc1 = __builtin_amdgcn_mfma_f32_16x16x32_bf16(wfrag[1][kt], ffrag, acc1, 0, 0, 0);
        }
        const int ge = edge_base + et * 16 + fe;
        f32x4 c0, c1;
        #pragma unroll
        for (int j = 0; j < 4; ++j) {
            c0[j] = fmaxf(acc0[j], 0.f);
            c1[j] = fmaxf(acc1[j], 0.f);
        }
        if (ge < E) {
            float* ep = e_out + (size_t)ge * 128 + n0 + (lane >> 4) * 4;
            *(f32x4*)ep        = c0;
            *(f32x4*)(ep + 16) = c1;
        }
        float pdot = c0[0]*wa[0][0] + c0[1]*wa[0][1] + c0[2]*wa[0][2] + c0[3]*wa[0][3]
                   + c1[0]*wa[1][0] + c1[1]*wa[1][1] + c1[2]*wa[1][2] + c1[3]*wa[1][3];
        pdot += __shfl_xor(pdot, 16);
        pdot += __shfl_xor(pdot, 32);
        if (lane < 16) atomicAdd(&a_acc[et * 16 + lane], pdot);
    }

    __syncthreads();
    if (tid < ME) {
        int ge = edge_base + tid;
        if (ge < E) {
            float a = a_acc[tid];
            a_out[ge] = (a > 0.f) ? a : NEG_SLOPE * a;
        }
    }
}

extern "C" void kernel_launch(void* const* d_in, const int* in_sizes, int n_in,
                              void* d_out, int out_size, void* d_ws, size_t ws_size,
                              hipStream_t stream) {
    const float* n_f     = (const float*)d_in[0];
    const int*   src_idx = (const int*)d_in[1];
    const int*   dst_idx = (const int*)d_in[2];
    const float* W_edge  = (const float*)d_in[3];
    const float* W_attn  = (const float*)d_in[4];
    const int E       = in_sizes[1];
    const int n_nodes = in_sizes[0] / 128;

    float* e_out = (float*)d_out;
    float* a_out = e_out + (size_t)E * 128;

    const size_t uv_b = (size_t)n_nodes * 256 * sizeof(unsigned short);
    if (ws_size >= uv_b) {
        unsigned short* uv = (unsigned short*)d_ws;
        int nb1 = (n_nodes + 63) / 64;
        node_gemm_kernel<<<nb1, 256, 0, stream>>>(n_f, W_edge, uv, n_nodes);
        edge_apply_kernel<<<2048, 256, 0, stream>>>(src_idx, dst_idx, uv, W_attn,
                                                    e_out, a_out, E);
    } else {
        int nblocks = (E + ME - 1) / ME;
        gat_edge_fused_kernel<<<nblocks, 256, 0, stream>>>(n_f, src_idx, dst_idx,
                                                           W_edge, W_attn, e_out, a_out, E);
    }
}